// Round 1
// baseline (13959.534 us; speedup 1.0000x reference)
//
#include <hip/hip_runtime.h>
#include <math.h>

#define V_SZ   65
#define C_DIM  512
#define T_SEQ  256
#define H_N    8
#define HS_D   64
#define L_N    8
#define N_TOK  16384   // B*T = 64*256
#define LN_EPS 1e-5f
#define SM_SCALE 0.044194173824159216f  // 512^-0.5 (scaled by n_embd, per reference)

// ---------------------------------------------------------------------------
// Embedding: x[n][c] = tok_emb[idx[n]][c] + pos_emb[n % T][c]
// ---------------------------------------------------------------------------
__global__ void embed_kernel(const int* __restrict__ idx,
                             const float* __restrict__ tok,
                             const float* __restrict__ pos,
                             float* __restrict__ x) {
    int i = blockIdx.x * blockDim.x + threadIdx.x;       // float4 index
    const int NF4 = N_TOK * C_DIM / 4;
    if (i >= NF4) return;
    int c4 = i % (C_DIM / 4);
    int n  = i / (C_DIM / 4);
    int t  = n % T_SEQ;
    int tk = idx[n];
    float4 a = ((const float4*)tok)[(size_t)tk * (C_DIM/4) + c4];
    float4 p = ((const float4*)pos)[(size_t)t  * (C_DIM/4) + c4];
    float4 r; r.x=a.x+p.x; r.y=a.y+p.y; r.z=a.z+p.z; r.w=a.w+p.w;
    ((float4*)x)[i] = r;
}

// ---------------------------------------------------------------------------
// LayerNorm: one wave (64 lanes) per row of C=512. 8 elems/lane.
// ---------------------------------------------------------------------------
__global__ __launch_bounds__(256) void ln_kernel(const float* __restrict__ in,
                                                 const float* __restrict__ g,
                                                 const float* __restrict__ b,
                                                 float* __restrict__ out) {
    int wave = threadIdx.x >> 6;
    int lane = threadIdx.x & 63;
    int row  = blockIdx.x * 4 + wave;
    const float* r = in + (size_t)row * C_DIM;
    float v[8];
    float s = 0.f;
    #pragma unroll
    for (int k = 0; k < 8; k++) { v[k] = r[lane + 64*k]; s += v[k]; }
    #pragma unroll
    for (int m = 32; m >= 1; m >>= 1) s += __shfl_xor(s, m, 64);
    float mean = s * (1.0f / C_DIM);
    float vs = 0.f;
    #pragma unroll
    for (int k = 0; k < 8; k++) { float d = v[k] - mean; vs += d * d; }
    #pragma unroll
    for (int m = 32; m >= 1; m >>= 1) vs += __shfl_xor(vs, m, 64);
    float rstd = rsqrtf(vs * (1.0f / C_DIM) + LN_EPS);
    float* o = out + (size_t)row * C_DIM;
    #pragma unroll
    for (int k = 0; k < 8; k++) {
        int c = lane + 64*k;
        o[c] = (v[k] - mean) * rstd * g[c] + b[c];
    }
}

// ---------------------------------------------------------------------------
// fp32 tiled GEMM: out[M,N] = epi(A[M,K] @ B[K,N])
// EPI: 0 none | 1 +bias | 2 +bias,relu | 3 +bias,+res
// BM=128, BN=64, BK=16, 256 threads, 8x4 per-thread micro-tile.
// ---------------------------------------------------------------------------
template<int EPI>
__global__ __launch_bounds__(256) void gemm_kernel(const float* __restrict__ A,
                                                   const float* __restrict__ B,
                                                   const float* __restrict__ bias,
                                                   const float* __restrict__ res,
                                                   float* __restrict__ out,
                                                   int M, int N, int K) {
    const int BM = 128, BN = 64, BK = 16;
    __shared__ float As[BK][BM + 4];   // stride 132 floats = 528B (16B-aligned rows)
    __shared__ float Bs[BK][BN + 4];   // stride 68 floats = 272B (16B-aligned rows)
    int tid = threadIdx.x;
    int tx = tid & 15;    // N dim: 16 * 4 = 64
    int ty = tid >> 4;    // M dim: 16 * 8 = 128
    int mBase = blockIdx.x * BM;
    int nBase = blockIdx.y * BN;
    // A load map: thread covers 8 consecutive k of one row
    int ar = tid >> 1;
    int ac = (tid & 1) * 8;
    // B load map: thread covers 4 consecutive n of one k-row
    int br = tid >> 4;
    int bc = (tid & 15) * 4;

    float acc[8][4] = {};

    for (int k0 = 0; k0 < K; k0 += BK) {
        float4 a0 = *(const float4*)&A[(size_t)(mBase + ar) * K + k0 + ac];
        float4 a1 = *(const float4*)&A[(size_t)(mBase + ar) * K + k0 + ac + 4];
        As[ac+0][ar] = a0.x; As[ac+1][ar] = a0.y; As[ac+2][ar] = a0.z; As[ac+3][ar] = a0.w;
        As[ac+4][ar] = a1.x; As[ac+5][ar] = a1.y; As[ac+6][ar] = a1.z; As[ac+7][ar] = a1.w;
        float4 b0 = *(const float4*)&B[(size_t)(k0 + br) * N + nBase + bc];
        *(float4*)&Bs[br][bc] = b0;
        __syncthreads();
        #pragma unroll
        for (int k = 0; k < BK; k++) {
            float a[8], bb[4];
            *(float4*)&a[0] = *(const float4*)&As[k][ty * 8];
            *(float4*)&a[4] = *(const float4*)&As[k][ty * 8 + 4];
            *(float4*)&bb[0] = *(const float4*)&Bs[k][tx * 4];
            #pragma unroll
            for (int i = 0; i < 8; i++)
                #pragma unroll
                for (int j = 0; j < 4; j++)
                    acc[i][j] = fmaf(a[i], bb[j], acc[i][j]);
        }
        __syncthreads();
    }

    int col = nBase + tx * 4;
    #pragma unroll
    for (int i = 0; i < 8; i++) {
        size_t row = (size_t)(mBase + ty * 8 + i);
        float4 r;
        float* pr = (float*)&r;
        #pragma unroll
        for (int j = 0; j < 4; j++) {
            float vv = acc[i][j];
            if (EPI >= 1) vv += bias[col + j];
            if (EPI == 2) vv = fmaxf(vv, 0.f);
            pr[j] = vv;
        }
        if (EPI == 3) {
            float4 rv = *(const float4*)&res[row * N + col];
            r.x += rv.x; r.y += rv.y; r.z += rv.z; r.w += rv.w;
        }
        *(float4*)&out[row * N + col] = r;
    }
}

// ---------------------------------------------------------------------------
// Attention: one block per (b,h). K,V staged in LDS (128 KiB).
// One thread per query row; lockstep j-loop -> broadcast LDS reads.
// ---------------------------------------------------------------------------
__global__ __launch_bounds__(256) void attn_kernel(const float* __restrict__ q,
                                                   const float* __restrict__ k,
                                                   const float* __restrict__ v,
                                                   float* __restrict__ att) {
    __shared__ float Ks[T_SEQ][HS_D];
    __shared__ float Vs[T_SEQ][HS_D];
    int bh = blockIdx.x;
    int b = bh / H_N, h = bh % H_N;
    int t = threadIdx.x;
    const size_t base = (size_t)b * T_SEQ * C_DIM + (size_t)h * HS_D;

    for (int f = threadIdx.x; f < T_SEQ * (HS_D / 4); f += 256) {
        int row = f / (HS_D / 4);
        int c4  = f % (HS_D / 4);
        ((float4*)&Ks[row][0])[c4] = *(const float4*)&k[base + (size_t)row * C_DIM + c4 * 4];
        ((float4*)&Vs[row][0])[c4] = *(const float4*)&v[base + (size_t)row * C_DIM + c4 * 4];
    }
    __syncthreads();

    float qr[HS_D];
    #pragma unroll
    for (int c4 = 0; c4 < HS_D / 4; c4++)
        *(float4*)&qr[c4 * 4] = *(const float4*)&q[base + (size_t)t * C_DIM + c4 * 4];

    // pass 1: row max
    float m = -1e30f;
    for (int j = 0; j <= t; j++) {
        float s = 0.f;
        #pragma unroll
        for (int d = 0; d < HS_D; d++) s = fmaf(qr[d], Ks[j][d], s);
        m = fmaxf(m, s * SM_SCALE);
    }
    // pass 2: exp-sum + PV
    float o[HS_D];
    #pragma unroll
    for (int d = 0; d < HS_D; d++) o[d] = 0.f;
    float se = 0.f;
    for (int j = 0; j <= t; j++) {
        float s = 0.f;
        #pragma unroll
        for (int d = 0; d < HS_D; d++) s = fmaf(qr[d], Ks[j][d], s);
        float e = __expf(s * SM_SCALE - m);
        se += e;
        #pragma unroll
        for (int d = 0; d < HS_D; d++) o[d] = fmaf(e, Vs[j][d], o[d]);
    }
    float inv = 1.0f / se;
    float* op = att + base + (size_t)t * C_DIM;
    #pragma unroll
    for (int d4 = 0; d4 < HS_D / 4; d4++) {
        float4 r;
        r.x = o[d4*4+0]*inv; r.y = o[d4*4+1]*inv;
        r.z = o[d4*4+2]*inv; r.w = o[d4*4+3]*inv;
        *(float4*)&op[d4 * 4] = r;
    }
}

// ---------------------------------------------------------------------------
// LM head: one block per token row; h row staged in LDS; 65 output cols.
// ---------------------------------------------------------------------------
__global__ __launch_bounds__(128) void logits_kernel(const float* __restrict__ h,
                                                     const float* __restrict__ w,
                                                     const float* __restrict__ bb,
                                                     float* __restrict__ out) {
    __shared__ float hs[C_DIM];
    int n = blockIdx.x;
    for (int c = threadIdx.x; c < C_DIM; c += blockDim.x)
        hs[c] = h[(size_t)n * C_DIM + c];
    __syncthreads();
    int j = threadIdx.x;
    if (j < V_SZ) {
        float s = bb[j];
        for (int c = 0; c < C_DIM; c++) s = fmaf(hs[c], w[(size_t)c * V_SZ + j], s);
        out[(size_t)n * V_SZ + j] = s;
    }
}

// ---------------------------------------------------------------------------
// Per-row -log_softmax[target]; one wave per row (V=65: lane0 also covers 64).
// ---------------------------------------------------------------------------
__global__ __launch_bounds__(256) void rowloss_kernel(const float* __restrict__ logits,
                                                      const int* __restrict__ tgt,
                                                      float* __restrict__ rl) {
    int wave = threadIdx.x >> 6, lane = threadIdx.x & 63;
    int n = blockIdx.x * 4 + wave;
    const float* l = logits + (size_t)n * V_SZ;
    float v0 = l[lane];
    float v1 = (lane == 0) ? l[64] : -1e30f;
    float m = fmaxf(v0, v1);
    #pragma unroll
    for (int s = 32; s >= 1; s >>= 1) m = fmaxf(m, __shfl_xor(m, s, 64));
    float e = __expf(v0 - m) + ((lane == 0) ? __expf(v1 - m) : 0.f);
    #pragma unroll
    for (int s = 32; s >= 1; s >>= 1) e += __shfl_xor(e, s, 64);
    if (lane == 0) {
        float lp = l[tgt[n]] - m - logf(e);
        rl[n] = -lp;
    }
}

// Deterministic single-block sum -> loss
__global__ __launch_bounds__(256) void reduce_loss_kernel(const float* __restrict__ rl,
                                                          float* __restrict__ out_loss) {
    __shared__ float sdata[256];
    float s = 0.f;
    for (int i = threadIdx.x; i < N_TOK; i += 256) s += rl[i];
    sdata[threadIdx.x] = s;
    __syncthreads();
    for (int st = 128; st > 0; st >>= 1) {
        if (threadIdx.x < st) sdata[threadIdx.x] += sdata[threadIdx.x + st];
        __syncthreads();
    }
    if (threadIdx.x == 0) out_loss[0] = sdata[0] * (1.0f / N_TOK);
}

// ---------------------------------------------------------------------------
extern "C" void kernel_launch(void* const* d_in, const int* in_sizes, int n_in,
                              void* d_out, int out_size, void* d_ws, size_t ws_size,
                              hipStream_t stream) {
    const int*   idx     = (const int*)d_in[0];
    const int*   targets = (const int*)d_in[1];
    const float* tok_emb = (const float*)d_in[2];
    const float* pos_emb = (const float*)d_in[3];
    const float* ln1_g   = (const float*)d_in[4];
    const float* ln1_b   = (const float*)d_in[5];
    const float* wq      = (const float*)d_in[6];
    const float* wk      = (const float*)d_in[7];
    const float* wv      = (const float*)d_in[8];
    const float* wo      = (const float*)d_in[9];
    const float* bo      = (const float*)d_in[10];
    const float* ln2_g   = (const float*)d_in[11];
    const float* ln2_b   = (const float*)d_in[12];
    const float* w1      = (const float*)d_in[13];
    const float* b1      = (const float*)d_in[14];
    const float* w2      = (const float*)d_in[15];
    const float* b2      = (const float*)d_in[16];
    const float* lnf_g   = (const float*)d_in[17];
    const float* lnf_b   = (const float*)d_in[18];
    const float* lm_w    = (const float*)d_in[19];
    const float* lm_b    = (const float*)d_in[20];

    float* out = (float*)d_out;
    char*  ws  = (char*)d_ws;
    const size_t MB = 1024ull * 1024ull;
    float* x   = (float*)(ws);                 // 32 MB
    float* h   = (float*)(ws + 32 * MB);       // 32 MB
    float* big = (float*)(ws + 64 * MB);       // 128 MB union {q,k,v,att} / {ff1}
    float* q   = big;
    float* k   = big + 8 * MB;                 // +32MB in floats
    float* v   = big + 16 * MB;
    float* att = big + 24 * MB;
    float* ff1 = big;                          // reuse after attention is consumed
    float* rl  = (float*)(ws + 192 * MB);      // 64 KB

    // 1. embedding
    embed_kernel<<<(N_TOK * C_DIM / 4 + 255) / 256, 256, 0, stream>>>(idx, tok_emb, pos_emb, x);

    dim3 gemmGridCC(N_TOK / 128, C_DIM / 64);        // 512-out GEMMs
    dim3 gemmGridC4(N_TOK / 128, (4 * C_DIM) / 64);  // 2048-out GEMM

    for (int l = 0; l < L_N; l++) {
        const float* wq_l = wq + (size_t)l * C_DIM * C_DIM;
        const float* wk_l = wk + (size_t)l * C_DIM * C_DIM;
        const float* wv_l = wv + (size_t)l * C_DIM * C_DIM;
        const float* wo_l = wo + (size_t)l * C_DIM * C_DIM;
        const float* w1_l = w1 + (size_t)l * C_DIM * 4 * C_DIM;
        const float* w2_l = w2 + (size_t)l * 4 * C_DIM * C_DIM;

        // ln1
        ln_kernel<<<N_TOK / 4, 256, 0, stream>>>(x, ln1_g + l * C_DIM, ln1_b + l * C_DIM, h);
        // qkv (no bias)
        gemm_kernel<0><<<gemmGridCC, 256, 0, stream>>>(h, wq_l, nullptr, nullptr, q, N_TOK, C_DIM, C_DIM);
        gemm_kernel<0><<<gemmGridCC, 256, 0, stream>>>(h, wk_l, nullptr, nullptr, k, N_TOK, C_DIM, C_DIM);
        gemm_kernel<0><<<gemmGridCC, 256, 0, stream>>>(h, wv_l, nullptr, nullptr, v, N_TOK, C_DIM, C_DIM);
        // attention
        attn_kernel<<<64 * H_N, 256, 0, stream>>>(q, k, v, att);
        // out proj + residual: x = x + att@wo + bo
        gemm_kernel<3><<<gemmGridCC, 256, 0, stream>>>(att, wo_l, bo + l * C_DIM, x, x, N_TOK, C_DIM, C_DIM);
        // ln2
        ln_kernel<<<N_TOK / 4, 256, 0, stream>>>(x, ln2_g + l * C_DIM, ln2_b + l * C_DIM, h);
        // ffn
        gemm_kernel<2><<<gemmGridC4, 256, 0, stream>>>(h, w1_l, b1 + (size_t)l * 4 * C_DIM, nullptr, ff1, N_TOK, 4 * C_DIM, C_DIM);
        gemm_kernel<3><<<gemmGridCC, 256, 0, stream>>>(ff1, w2_l, b2 + l * C_DIM, x, x, N_TOK, C_DIM, 4 * C_DIM);
    }

    // final LN + LM head
    ln_kernel<<<N_TOK / 4, 256, 0, stream>>>(x, lnf_g, lnf_b, h);
    logits_kernel<<<N_TOK, 128, 0, stream>>>(h, lm_w, lm_b, out);

    // loss
    rowloss_kernel<<<N_TOK / 4, 256, 0, stream>>>(out, targets, rl);
    reduce_loss_kernel<<<1, 256, 0, stream>>>(rl, out + (size_t)N_TOK * V_SZ);
}

// Round 2
// 4067.250 us; speedup vs baseline: 3.4322x; 3.4322x over previous
//
#include <hip/hip_runtime.h>
#include <math.h>

#define V_SZ   65
#define C_DIM  512
#define T_SEQ  256
#define H_N    8
#define HS_D   64
#define L_N    8
#define N_TOK  16384   // B*T = 64*256
#define LN_EPS 1e-5f
#define SM_SCALE 0.044194173824159216f  // 512^-0.5 (scaled by n_embd, per reference)

typedef unsigned short ushortT;
typedef __attribute__((ext_vector_type(8))) short    short8;
typedef __attribute__((ext_vector_type(8))) ushortT  ushort8;
typedef __attribute__((ext_vector_type(4))) float    f32x4;

__device__ inline ushortT f2bf(float f) {
    unsigned int u = __float_as_uint(f);
    u = (u + 0x7fffu + ((u >> 16) & 1u)) >> 16;   // RNE
    return (ushortT)u;
}
__device__ inline float bf2f(ushortT u) {
    return __uint_as_float(((unsigned int)u) << 16);
}

// ---------------------------------------------------------------------------
// Embedding: x[n][c] = tok_emb[idx[n]][c] + pos_emb[n % T][c]   (fp32)
// ---------------------------------------------------------------------------
__global__ void embed_kernel(const int* __restrict__ idx,
                             const float* __restrict__ tok,
                             const float* __restrict__ pos,
                             float* __restrict__ x) {
    int i = blockIdx.x * blockDim.x + threadIdx.x;
    const int NF4 = N_TOK * C_DIM / 4;
    if (i >= NF4) return;
    int c4 = i % (C_DIM / 4);
    int n  = i / (C_DIM / 4);
    int t  = n % T_SEQ;
    int tk = idx[n];
    float4 a = ((const float4*)tok)[(size_t)tk * (C_DIM/4) + c4];
    float4 p = ((const float4*)pos)[(size_t)t  * (C_DIM/4) + c4];
    float4 r; r.x=a.x+p.x; r.y=a.y+p.y; r.z=a.z+p.z; r.w=a.w+p.w;
    ((float4*)x)[i] = r;
}

// ---------------------------------------------------------------------------
// Weight transpose+cast: src[K][N] f32 -> dst[N][K] bf16, batched over L.
// ---------------------------------------------------------------------------
__global__ __launch_bounds__(256) void tcast_kernel(const float* __restrict__ src,
                                                    ushortT* __restrict__ dst,
                                                    int K, int N) {
    __shared__ float tile[32][33];
    size_t lo = (size_t)blockIdx.z * K * N;
    int n0 = blockIdx.x * 32, k0 = blockIdx.y * 32;
    int tx = threadIdx.x & 31, ty = threadIdx.x >> 5;   // 32 x 8
    #pragma unroll
    for (int s = 0; s < 4; s++) {
        int kk = ty + s * 8;
        tile[kk][tx] = src[lo + (size_t)(k0 + kk) * N + n0 + tx];
    }
    __syncthreads();
    #pragma unroll
    for (int s = 0; s < 4; s++) {
        int nn = ty + s * 8;
        dst[lo + (size_t)(n0 + nn) * K + k0 + tx] = f2bf(tile[tx][nn]);
    }
}

// ---------------------------------------------------------------------------
// LayerNorm: one wave per row of C=512. Templated output dtype.
// ---------------------------------------------------------------------------
template<bool BF16OUT>
__global__ __launch_bounds__(256) void ln_kernel(const float* __restrict__ in,
                                                 const float* __restrict__ g,
                                                 const float* __restrict__ b,
                                                 void* __restrict__ outv) {
    int wave = threadIdx.x >> 6;
    int lane = threadIdx.x & 63;
    int row  = blockIdx.x * 4 + wave;
    const float* r = in + (size_t)row * C_DIM;
    float v[8];
    float s = 0.f;
    #pragma unroll
    for (int k = 0; k < 8; k++) { v[k] = r[lane + 64*k]; s += v[k]; }
    #pragma unroll
    for (int m = 32; m >= 1; m >>= 1) s += __shfl_xor(s, m, 64);
    float mean = s * (1.0f / C_DIM);
    float vs = 0.f;
    #pragma unroll
    for (int k = 0; k < 8; k++) { float d = v[k] - mean; vs += d * d; }
    #pragma unroll
    for (int m = 32; m >= 1; m >>= 1) vs += __shfl_xor(vs, m, 64);
    float rstd = rsqrtf(vs * (1.0f / C_DIM) + LN_EPS);
    #pragma unroll
    for (int k = 0; k < 8; k++) {
        int c = lane + 64*k;
        float val = (v[k] - mean) * rstd * g[c] + b[c];
        if (BF16OUT) ((ushortT*)outv)[(size_t)row * C_DIM + c] = f2bf(val);
        else         ((float*)outv)[(size_t)row * C_DIM + c] = val;
    }
}

// ---------------------------------------------------------------------------
// bf16 MFMA GEMM: C[M,N] = epi(A[M,K] @ Bt[N,K]^T)
// A row-major bf16, Bt row-major bf16 (= B transposed).
// 128x128 tile, BK=32, 256 thr = 4 waves (2x2), each wave 64x64 via 4x4 MFMA.
// EPI: 0 fp32 store | 1 bf16 store | 2 +bias,relu -> bf16 | 3 +bias,+res -> fp32
// ---------------------------------------------------------------------------
template<int EPI>
__global__ __launch_bounds__(256, 2) void gemm_bf16(const ushortT* __restrict__ A,
                                                    const ushortT* __restrict__ Bt,
                                                    const float* __restrict__ bias,
                                                    const float* __restrict__ res,
                                                    void* __restrict__ outp,
                                                    int M, int N, int K) {
    __shared__ ushortT As[128][40];   // padded: rows 80B -> frag reads 2-way banks (free)
    __shared__ ushortT Bs[128][40];
    int tid  = threadIdx.x;
    int w    = tid >> 6, lane = tid & 63;
    int wr   = w >> 1,  wc   = w & 1;
    int mBase = blockIdx.x * 128, nBase = blockIdx.y * 128;

    f32x4 acc[4][4];
    #pragma unroll
    for (int i = 0; i < 4; i++)
        #pragma unroll
        for (int j = 0; j < 4; j++)
            acc[i][j] = {0.f, 0.f, 0.f, 0.f};

    for (int k0 = 0; k0 < K; k0 += 32) {
        // stage 128x32 of A and Bt (16B chunks, lane-consecutive -> coalesced)
        #pragma unroll
        for (int i = 0; i < 2; i++) {
            int c  = i * 256 + tid;       // chunk 0..511
            int r  = c >> 2, kp = c & 3;
            ushort8 a = *(const ushort8*)&A [(size_t)(mBase + r) * K + k0 + kp * 8];
            *(ushort8*)&As[r][kp * 8] = a;
            ushort8 b = *(const ushort8*)&Bt[(size_t)(nBase + r) * K + k0 + kp * 8];
            *(ushort8*)&Bs[r][kp * 8] = b;
        }
        __syncthreads();
        short8 af[4], bfr[4];
        #pragma unroll
        for (int i = 0; i < 4; i++)
            af[i]  = *(const short8*)&As[wr * 64 + i * 16 + (lane & 15)][(lane >> 4) * 8];
        #pragma unroll
        for (int j = 0; j < 4; j++)
            bfr[j] = *(const short8*)&Bs[wc * 64 + j * 16 + (lane & 15)][(lane >> 4) * 8];
        #pragma unroll
        for (int i = 0; i < 4; i++)
            #pragma unroll
            for (int j = 0; j < 4; j++)
                acc[i][j] = __builtin_amdgcn_mfma_f32_16x16x32_bf16(af[i], bfr[j], acc[i][j], 0, 0, 0);
        __syncthreads();
    }

    // epilogue: C/D layout col=lane&15, row=(lane>>4)*4+q  [m89-verified]
    int lr = (lane >> 4) * 4, lc = lane & 15;
    #pragma unroll
    for (int i = 0; i < 4; i++) {
        #pragma unroll
        for (int j = 0; j < 4; j++) {
            int col = nBase + wc * 64 + j * 16 + lc;
            #pragma unroll
            for (int q = 0; q < 4; q++) {
                size_t row = (size_t)(mBase + wr * 64 + i * 16 + lr + q);
                float vv = acc[i][j][q];
                if (EPI >= 2) vv += bias[col];
                if (EPI == 2) vv = fmaxf(vv, 0.f);
                if (EPI == 3) vv += res[row * N + col];
                if (EPI == 0)      ((float*)outp)[row * N + col]   = vv;
                else if (EPI == 1) ((ushortT*)outp)[row * N + col] = f2bf(vv);
                else if (EPI == 2) ((ushortT*)outp)[row * N + col] = f2bf(vv);
                else               ((float*)outp)[row * N + col]   = vv;
            }
        }
    }
}

// ---------------------------------------------------------------------------
// Attention: block per (b,h), 256 thr (1 query/thread), single-pass online
// softmax. K staged LDS f32 (64KB -> 2 blocks/CU); V fp32 broadcast from L2;
// q,k bf16 inputs; bf16 output. SM_SCALE folded into q registers.
// ---------------------------------------------------------------------------
__global__ __launch_bounds__(256) void attn_kernel(const ushortT* __restrict__ q,
                                                   const ushortT* __restrict__ k,
                                                   const float* __restrict__ v,
                                                   ushortT* __restrict__ att) {
    __shared__ float Ks[T_SEQ][HS_D];   // 64 KB
    int bh = blockIdx.x;
    int b = bh >> 3, h = bh & 7;
    int t = threadIdx.x;
    const size_t rowbase = (size_t)b * T_SEQ * C_DIM + (size_t)h * HS_D;

    for (int f = t; f < T_SEQ * 8; f += 256) {      // 256 rows x 8 chunks
        int r = f >> 3, c8 = f & 7;
        ushort8 kb = *(const ushort8*)&k[rowbase + (size_t)r * C_DIM + c8 * 8];
        float tmp[8];
        #pragma unroll
        for (int e = 0; e < 8; e++) tmp[e] = bf2f(kb[e]);
        *(float4*)&Ks[r][c8 * 8]     = *(float4*)&tmp[0];
        *(float4*)&Ks[r][c8 * 8 + 4] = *(float4*)&tmp[4];
    }

    float qr[HS_D];
    #pragma unroll
    for (int c8 = 0; c8 < 8; c8++) {
        ushort8 qb = *(const ushort8*)&q[rowbase + (size_t)t * C_DIM + c8 * 8];
        #pragma unroll
        for (int e = 0; e < 8; e++) qr[c8 * 8 + e] = bf2f(qb[e]) * SM_SCALE;
    }
    __syncthreads();

    float m = -1e30f, se = 0.f;
    float o[HS_D];
    #pragma unroll
    for (int d = 0; d < HS_D; d++) o[d] = 0.f;
    const float* vbase = v + rowbase;

    for (int j = 0; j <= t; j++) {
        float s = 0.f;
        const float4* kr = (const float4*)&Ks[j][0];
        #pragma unroll
        for (int c = 0; c < 16; c++) {
            float4 kv = kr[c];
            s = fmaf(qr[c*4+0], kv.x, s);
            s = fmaf(qr[c*4+1], kv.y, s);
            s = fmaf(qr[c*4+2], kv.z, s);
            s = fmaf(qr[c*4+3], kv.w, s);
        }
        if (s > m) {                      // rare after warm-up
            float corr = __expf(m - s);
            se *= corr;
            #pragma unroll
            for (int d = 0; d < HS_D; d++) o[d] *= corr;
            m = s;
        }
        float e = __expf(s - m);
        se += e;
        const float4* vr = (const float4*)&vbase[(size_t)j * C_DIM];
        #pragma unroll
        for (int c = 0; c < 16; c++) {
            float4 vv = vr[c];
            o[c*4+0] = fmaf(e, vv.x, o[c*4+0]);
            o[c*4+1] = fmaf(e, vv.y, o[c*4+1]);
            o[c*4+2] = fmaf(e, vv.z, o[c*4+2]);
            o[c*4+3] = fmaf(e, vv.w, o[c*4+3]);
        }
    }
    float inv = 1.0f / se;
    ushortT* op = att + rowbase + (size_t)t * C_DIM;
    #pragma unroll
    for (int c8 = 0; c8 < 8; c8++) {
        ushort8 pack;
        #pragma unroll
        for (int e = 0; e < 8; e++) pack[e] = f2bf(o[c8 * 8 + e] * inv);
        *(ushort8*)&op[c8 * 8] = pack;
    }
}

// ---------------------------------------------------------------------------
// LM head (fp32): one block per token row; h row staged in LDS; 65 cols.
// ---------------------------------------------------------------------------
__global__ __launch_bounds__(128) void logits_kernel(const float* __restrict__ h,
                                                     const float* __restrict__ w,
                                                     const float* __restrict__ bb,
                                                     float* __restrict__ out) {
    __shared__ float hs[C_DIM];
    int n = blockIdx.x;
    for (int c = threadIdx.x; c < C_DIM; c += blockDim.x)
        hs[c] = h[(size_t)n * C_DIM + c];
    __syncthreads();
    int j = threadIdx.x;
    if (j < V_SZ) {
        float s = bb[j];
        for (int c = 0; c < C_DIM; c++) s = fmaf(hs[c], w[(size_t)c * V_SZ + j], s);
        out[(size_t)n * V_SZ + j] = s;
    }
}

__global__ __launch_bounds__(256) void rowloss_kernel(const float* __restrict__ logits,
                                                      const int* __restrict__ tgt,
                                                      float* __restrict__ rl) {
    int wave = threadIdx.x >> 6, lane = threadIdx.x & 63;
    int n = blockIdx.x * 4 + wave;
    const float* l = logits + (size_t)n * V_SZ;
    float v0 = l[lane];
    float v1 = (lane == 0) ? l[64] : -1e30f;
    float m = fmaxf(v0, v1);
    #pragma unroll
    for (int s = 32; s >= 1; s >>= 1) m = fmaxf(m, __shfl_xor(m, s, 64));
    float e = __expf(v0 - m) + ((lane == 0) ? __expf(v1 - m) : 0.f);
    #pragma unroll
    for (int s = 32; s >= 1; s >>= 1) e += __shfl_xor(e, s, 64);
    if (lane == 0) {
        float lp = l[tgt[n]] - m - logf(e);
        rl[n] = -lp;
    }
}

__global__ __launch_bounds__(256) void reduce_loss_kernel(const float* __restrict__ rl,
                                                          float* __restrict__ out_loss) {
    __shared__ float sdata[256];
    float s = 0.f;
    for (int i = threadIdx.x; i < N_TOK; i += 256) s += rl[i];
    sdata[threadIdx.x] = s;
    __syncthreads();
    for (int st = 128; st > 0; st >>= 1) {
        if (threadIdx.x < st) sdata[threadIdx.x] += sdata[threadIdx.x + st];
        __syncthreads();
    }
    if (threadIdx.x == 0) out_loss[0] = sdata[0] * (1.0f / N_TOK);
}

// ---------------------------------------------------------------------------
extern "C" void kernel_launch(void* const* d_in, const int* in_sizes, int n_in,
                              void* d_out, int out_size, void* d_ws, size_t ws_size,
                              hipStream_t stream) {
    const int*   idx     = (const int*)d_in[0];
    const int*   targets = (const int*)d_in[1];
    const float* tok_emb = (const float*)d_in[2];
    const float* pos_emb = (const float*)d_in[3];
    const float* ln1_g   = (const float*)d_in[4];
    const float* ln1_b   = (const float*)d_in[5];
    const float* wq      = (const float*)d_in[6];
    const float* wk      = (const float*)d_in[7];
    const float* wv      = (const float*)d_in[8];
    const float* wo      = (const float*)d_in[9];
    const float* bo      = (const float*)d_in[10];
    const float* ln2_g   = (const float*)d_in[11];
    const float* ln2_b   = (const float*)d_in[12];
    const float* w1      = (const float*)d_in[13];
    const float* b1      = (const float*)d_in[14];
    const float* w2      = (const float*)d_in[15];
    const float* b2      = (const float*)d_in[16];
    const float* lnf_g   = (const float*)d_in[17];
    const float* lnf_b   = (const float*)d_in[18];
    const float* lm_w    = (const float*)d_in[19];
    const float* lm_b    = (const float*)d_in[20];

    float* out = (float*)d_out;
    char*  ws  = (char*)d_ws;
    const size_t MB = 1024ull * 1024ull;
    // layout (MB offsets):
    float*   x     = (float*)(ws);               // 0..32   fp32 residual
    ushortT* h_bf  = (ushortT*)(ws + 32 * MB);   // 32..48  bf16 LN out
    ushortT* q_bf  = (ushortT*)(ws + 48 * MB);   // 48..64
    ushortT* k_bf  = (ushortT*)(ws + 64 * MB);   // 64..80
    float*   v_f   = (float*)(ws + 80 * MB);     // 80..112 fp32
    ushortT* att_bf= (ushortT*)(ws + 112 * MB);  // 112..128
    ushortT* ff1_bf= (ushortT*)(ws + 48 * MB);   // 48..112 (reuses q/k/v region)
    float*   h32   = (float*)(ws + 48 * MB);     // lnf out (after last layer)
    ushortT* wqT   = (ushortT*)(ws + 128 * MB);  // each 4MB
    ushortT* wkT   = (ushortT*)(ws + 132 * MB);
    ushortT* wvT   = (ushortT*)(ws + 136 * MB);
    ushortT* woT   = (ushortT*)(ws + 140 * MB);
    ushortT* w1T   = (ushortT*)(ws + 144 * MB);  // 16MB
    ushortT* w2T   = (ushortT*)(ws + 160 * MB);  // 16MB
    float*   rl    = (float*)(ws + 176 * MB);

    // ---- weight prep (transpose + cast to bf16), batched over L ----
    {
        dim3 gCC(C_DIM / 32, C_DIM / 32, L_N);
        tcast_kernel<<<gCC, 256, 0, stream>>>(wq, wqT, C_DIM, C_DIM);
        tcast_kernel<<<gCC, 256, 0, stream>>>(wk, wkT, C_DIM, C_DIM);
        tcast_kernel<<<gCC, 256, 0, stream>>>(wv, wvT, C_DIM, C_DIM);
        tcast_kernel<<<gCC, 256, 0, stream>>>(wo, woT, C_DIM, C_DIM);
        dim3 g1(4 * C_DIM / 32, C_DIM / 32, L_N);
        tcast_kernel<<<g1, 256, 0, stream>>>(w1, w1T, C_DIM, 4 * C_DIM);
        dim3 g2(C_DIM / 32, 4 * C_DIM / 32, L_N);
        tcast_kernel<<<g2, 256, 0, stream>>>(w2, w2T, 4 * C_DIM, C_DIM);
    }

    embed_kernel<<<(N_TOK * C_DIM / 4 + 255) / 256, 256, 0, stream>>>(idx, tok_emb, pos_emb, x);

    dim3 gemmCC(N_TOK / 128, C_DIM / 128);          // (128, 4)
    dim3 gemmC4(N_TOK / 128, 4 * C_DIM / 128);      // (128, 16)

    for (int l = 0; l < L_N; l++) {
        const ushortT* wqT_l = wqT + (size_t)l * C_DIM * C_DIM;
        const ushortT* wkT_l = wkT + (size_t)l * C_DIM * C_DIM;
        const ushortT* wvT_l = wvT + (size_t)l * C_DIM * C_DIM;
        const ushortT* woT_l = woT + (size_t)l * C_DIM * C_DIM;
        const ushortT* w1T_l = w1T + (size_t)l * C_DIM * 4 * C_DIM;
        const ushortT* w2T_l = w2T + (size_t)l * C_DIM * 4 * C_DIM;

        ln_kernel<true><<<N_TOK / 4, 256, 0, stream>>>(x, ln1_g + l * C_DIM, ln1_b + l * C_DIM, h_bf);
        gemm_bf16<1><<<gemmCC, 256, 0, stream>>>(h_bf, wqT_l, nullptr, nullptr, q_bf, N_TOK, C_DIM, C_DIM);
        gemm_bf16<1><<<gemmCC, 256, 0, stream>>>(h_bf, wkT_l, nullptr, nullptr, k_bf, N_TOK, C_DIM, C_DIM);
        gemm_bf16<0><<<gemmCC, 256, 0, stream>>>(h_bf, wvT_l, nullptr, nullptr, v_f, N_TOK, C_DIM, C_DIM);
        attn_kernel<<<64 * H_N, 256, 0, stream>>>(q_bf, k_bf, v_f, att_bf);
        gemm_bf16<3><<<gemmCC, 256, 0, stream>>>(att_bf, woT_l, bo + l * C_DIM, x, x, N_TOK, C_DIM, C_DIM);
        ln_kernel<true><<<N_TOK / 4, 256, 0, stream>>>(x, ln2_g + l * C_DIM, ln2_b + l * C_DIM, h_bf);
        gemm_bf16<2><<<gemmC4, 256, 0, stream>>>(h_bf, w1T_l, b1 + (size_t)l * 4 * C_DIM, nullptr, ff1_bf, N_TOK, 4 * C_DIM, C_DIM);
        gemm_bf16<3><<<gemmCC, 256, 0, stream>>>(ff1_bf, w2T_l, b2 + l * C_DIM, x, x, N_TOK, C_DIM, 4 * C_DIM);
    }

    ln_kernel<false><<<N_TOK / 4, 256, 0, stream>>>(x, lnf_g, lnf_b, h32);
    logits_kernel<<<N_TOK, 128, 0, stream>>>(h32, lm_w, lm_b, out);

    rowloss_kernel<<<N_TOK / 4, 256, 0, stream>>>(out, targets, rl);
    reduce_loss_kernel<<<1, 256, 0, stream>>>(rl, out + (size_t)N_TOK * V_SZ);
}

// Round 3
// 2035.960 us; speedup vs baseline: 6.8565x; 1.9977x over previous
//
#include <hip/hip_runtime.h>
#include <math.h>

#define V_SZ   65
#define C_DIM  512
#define T_SEQ  256
#define H_N    8
#define HS_D   64
#define L_N    8
#define N_TOK  16384   // B*T = 64*256
#define LN_EPS 1e-5f
#define SM_SCALE 0.044194173824159216f  // 512^-0.5 (scaled by n_embd, per reference)

typedef unsigned short ushortT;
typedef __attribute__((ext_vector_type(8))) short    short8;
typedef __attribute__((ext_vector_type(8))) ushortT  ushort8;
typedef __attribute__((ext_vector_type(4))) float    f32x4;

__device__ inline ushortT f2bf(float f) {
    unsigned int u = __float_as_uint(f);
    u = (u + 0x7fffu + ((u >> 16) & 1u)) >> 16;   // RNE
    return (ushortT)u;
}
__device__ inline float bf2f(ushortT u) {
    return __uint_as_float(((unsigned int)u) << 16);
}

// ---------------------------------------------------------------------------
// Embedding: x[n][c] = tok_emb[idx[n]][c] + pos_emb[n % T][c]   (fp32)
// ---------------------------------------------------------------------------
__global__ void embed_kernel(const int* __restrict__ idx,
                             const float* __restrict__ tok,
                             const float* __restrict__ pos,
                             float* __restrict__ x) {
    int i = blockIdx.x * blockDim.x + threadIdx.x;
    const int NF4 = N_TOK * C_DIM / 4;
    if (i >= NF4) return;
    int c4 = i % (C_DIM / 4);
    int n  = i / (C_DIM / 4);
    int t  = n % T_SEQ;
    int tk = idx[n];
    float4 a = ((const float4*)tok)[(size_t)tk * (C_DIM/4) + c4];
    float4 p = ((const float4*)pos)[(size_t)t  * (C_DIM/4) + c4];
    float4 r; r.x=a.x+p.x; r.y=a.y+p.y; r.z=a.z+p.z; r.w=a.w+p.w;
    ((float4*)x)[i] = r;
}

// ---------------------------------------------------------------------------
// Weight transpose+cast: src[K][N] f32 -> dst[N][K] bf16, batched over L.
// ---------------------------------------------------------------------------
__global__ __launch_bounds__(256) void tcast_kernel(const float* __restrict__ src,
                                                    ushortT* __restrict__ dst,
                                                    int K, int N) {
    __shared__ float tile[32][33];
    size_t lo = (size_t)blockIdx.z * K * N;
    int n0 = blockIdx.x * 32, k0 = blockIdx.y * 32;
    int tx = threadIdx.x & 31, ty = threadIdx.x >> 5;   // 32 x 8
    #pragma unroll
    for (int s = 0; s < 4; s++) {
        int kk = ty + s * 8;
        tile[kk][tx] = src[lo + (size_t)(k0 + kk) * N + n0 + tx];
    }
    __syncthreads();
    #pragma unroll
    for (int s = 0; s < 4; s++) {
        int nn = ty + s * 8;
        dst[lo + (size_t)(n0 + nn) * K + k0 + tx] = f2bf(tile[tx][nn]);
    }
}

// ---------------------------------------------------------------------------
// LayerNorm: one wave per row of C=512. Templated output dtype.
// ---------------------------------------------------------------------------
template<bool BF16OUT>
__global__ __launch_bounds__(256) void ln_kernel(const float* __restrict__ in,
                                                 const float* __restrict__ g,
                                                 const float* __restrict__ b,
                                                 void* __restrict__ outv) {
    int wave = threadIdx.x >> 6;
    int lane = threadIdx.x & 63;
    int row  = blockIdx.x * 4 + wave;
    const float* r = in + (size_t)row * C_DIM;
    float v[8];
    float s = 0.f;
    #pragma unroll
    for (int k = 0; k < 8; k++) { v[k] = r[lane + 64*k]; s += v[k]; }
    #pragma unroll
    for (int m = 32; m >= 1; m >>= 1) s += __shfl_xor(s, m, 64);
    float mean = s * (1.0f / C_DIM);
    float vs = 0.f;
    #pragma unroll
    for (int k = 0; k < 8; k++) { float d = v[k] - mean; vs += d * d; }
    #pragma unroll
    for (int m = 32; m >= 1; m >>= 1) vs += __shfl_xor(vs, m, 64);
    float rstd = rsqrtf(vs * (1.0f / C_DIM) + LN_EPS);
    #pragma unroll
    for (int k = 0; k < 8; k++) {
        int c = lane + 64*k;
        float val = (v[k] - mean) * rstd * g[c] + b[c];
        if (BF16OUT) ((ushortT*)outv)[(size_t)row * C_DIM + c] = f2bf(val);
        else         ((float*)outv)[(size_t)row * C_DIM + c] = val;
    }
}

// ---------------------------------------------------------------------------
// bf16 MFMA GEMM: C[M,N] = epi(A[M,K] @ Bt[N,K]^T)
// 128x128 tile, BK=32, 4 waves (2x2), each wave 64x64 via 4x4 MFMA.
// EPI: 0 fp32 store | 1 bf16 store | 2 +bias,relu -> bf16 | 3 +bias,+res -> fp32
// ---------------------------------------------------------------------------
template<int EPI>
__global__ __launch_bounds__(256, 2) void gemm_bf16(const ushortT* __restrict__ A,
                                                    const ushortT* __restrict__ Bt,
                                                    const float* __restrict__ bias,
                                                    const float* __restrict__ res,
                                                    void* __restrict__ outp,
                                                    int M, int N, int K) {
    __shared__ ushortT As[128][40];
    __shared__ ushortT Bs[128][40];
    int tid  = threadIdx.x;
    int w    = tid >> 6, lane = tid & 63;
    int wr   = w >> 1,  wc   = w & 1;
    int mBase = blockIdx.x * 128, nBase = blockIdx.y * 128;

    f32x4 acc[4][4];
    #pragma unroll
    for (int i = 0; i < 4; i++)
        #pragma unroll
        for (int j = 0; j < 4; j++)
            acc[i][j] = {0.f, 0.f, 0.f, 0.f};

    for (int k0 = 0; k0 < K; k0 += 32) {
        #pragma unroll
        for (int i = 0; i < 2; i++) {
            int c  = i * 256 + tid;
            int r  = c >> 2, kp = c & 3;
            ushort8 a = *(const ushort8*)&A [(size_t)(mBase + r) * K + k0 + kp * 8];
            *(ushort8*)&As[r][kp * 8] = a;
            ushort8 b = *(const ushort8*)&Bt[(size_t)(nBase + r) * K + k0 + kp * 8];
            *(ushort8*)&Bs[r][kp * 8] = b;
        }
        __syncthreads();
        short8 af[4], bfr[4];
        #pragma unroll
        for (int i = 0; i < 4; i++)
            af[i]  = *(const short8*)&As[wr * 64 + i * 16 + (lane & 15)][(lane >> 4) * 8];
        #pragma unroll
        for (int j = 0; j < 4; j++)
            bfr[j] = *(const short8*)&Bs[wc * 64 + j * 16 + (lane & 15)][(lane >> 4) * 8];
        #pragma unroll
        for (int i = 0; i < 4; i++)
            #pragma unroll
            for (int j = 0; j < 4; j++)
                acc[i][j] = __builtin_amdgcn_mfma_f32_16x16x32_bf16(af[i], bfr[j], acc[i][j], 0, 0, 0);
        __syncthreads();
    }

    int lr = (lane >> 4) * 4, lc = lane & 15;
    #pragma unroll
    for (int i = 0; i < 4; i++) {
        #pragma unroll
        for (int j = 0; j < 4; j++) {
            int col = nBase + wc * 64 + j * 16 + lc;
            #pragma unroll
            for (int q = 0; q < 4; q++) {
                size_t row = (size_t)(mBase + wr * 64 + i * 16 + lr + q);
                float vv = acc[i][j][q];
                if (EPI >= 2) vv += bias[col];
                if (EPI == 2) vv = fmaxf(vv, 0.f);
                if (EPI == 3) vv += res[row * N + col];
                if (EPI == 0)      ((float*)outp)[row * N + col]   = vv;
                else if (EPI == 1) ((ushortT*)outp)[row * N + col] = f2bf(vv);
                else if (EPI == 2) ((ushortT*)outp)[row * N + col] = f2bf(vv);
                else               ((float*)outp)[row * N + col]   = vv;
            }
        }
    }
}

// ---------------------------------------------------------------------------
// MFMA flash attention: one block per (b,h), 4 waves.
// Wave w owns 16-row q-subtiles at rows 16*(4i+w), i=0..3 (balanced causal).
// K_lds [256][72] bf16; Vt_lds [64][264] bf16 (transposed); P per-wave [16][72].
// Online softmax, per-lane partial l reduced once at the end.
// ---------------------------------------------------------------------------
__global__ __launch_bounds__(256) void attn_kernel(const ushortT* __restrict__ qp,
                                                   const ushortT* __restrict__ kp,
                                                   const ushortT* __restrict__ vp,
                                                   ushortT* __restrict__ att) {
    __shared__ ushortT K_lds[T_SEQ][72];        // 36,864 B
    __shared__ ushortT Vt_lds[HS_D][264];       // 33,792 B
    __shared__ ushortT P_lds[4][16][72];        //  9,216 B   (total 79,872 B)
    int bh = blockIdx.x;
    int b = bh >> 3, h = bh & 7;
    int tid = threadIdx.x;
    int w = tid >> 6, lane = tid & 63;
    const size_t rowbase = (size_t)b * T_SEQ * C_DIM + (size_t)h * HS_D;
    int l15 = lane & 15, lg = lane >> 4;

    // stage K [key][d] and V transposed [d][key]
    #pragma unroll
    for (int it = 0; it < 8; it++) {
        int f = tid + it * 256;
        int r = f >> 3, c8 = f & 7;
        ushort8 kb = *(const ushort8*)&kp[rowbase + (size_t)r * C_DIM + c8 * 8];
        *(ushort8*)&K_lds[r][c8 * 8] = kb;
        ushort8 vb = *(const ushort8*)&vp[rowbase + (size_t)r * C_DIM + c8 * 8];
        #pragma unroll
        for (int e = 0; e < 8; e++) Vt_lds[c8 * 8 + e][r] = vb[e];
    }

    // Q A-fragments direct from global: row=lane&15 within subtile, k=(lane>>4)*8
    short8 qf[4][2];
    #pragma unroll
    for (int i = 0; i < 4; i++) {
        int grow = 16 * (4 * i + w) + l15;
        #pragma unroll
        for (int kk = 0; kk < 2; kk++)
            qf[i][kk] = *(const short8*)&qp[rowbase + (size_t)grow * C_DIM + kk * 32 + lg * 8];
    }
    __syncthreads();

    f32x4 acc_o[4][4];   // [i][dj]
    float mrun[4][4], lrun[4][4];   // [i][q]
    #pragma unroll
    for (int i = 0; i < 4; i++) {
        #pragma unroll
        for (int j = 0; j < 4; j++) acc_o[i][j] = {0.f, 0.f, 0.f, 0.f};
        #pragma unroll
        for (int q = 0; q < 4; q++) { mrun[i][q] = -1e30f; lrun[i][q] = 0.f; }
    }

    #pragma unroll
    for (int jt = 0; jt < 4; jt++) {
        #pragma unroll
        for (int i = 0; i < 4; i++) {
            if (i < jt) continue;   // causal: subtile i needs KV tile jt iff i >= jt
            // ---- S = Q_i @ K_tile^T  (16 x 64) ----
            f32x4 acc_s[4];
            #pragma unroll
            for (int j_ = 0; j_ < 4; j_++) acc_s[j_] = {0.f, 0.f, 0.f, 0.f};
            #pragma unroll
            for (int j_ = 0; j_ < 4; j_++)
                #pragma unroll
                for (int kk = 0; kk < 2; kk++) {
                    short8 kf = *(const short8*)&K_lds[jt * 64 + j_ * 16 + l15][kk * 32 + lg * 8];
                    acc_s[j_] = __builtin_amdgcn_mfma_f32_16x16x32_bf16(qf[i][kk], kf, acc_s[j_], 0, 0, 0);
                }
            // ---- scale + causal mask (only diagonal: i==jt) ----
            float sv[4][4];
            #pragma unroll
            for (int j_ = 0; j_ < 4; j_++) {
                int colg = jt * 64 + j_ * 16 + l15;
                #pragma unroll
                for (int q = 0; q < 4; q++) {
                    int rowg = 16 * (4 * i + w) + lg * 4 + q;
                    float s = acc_s[j_][q] * SM_SCALE;
                    sv[j_][q] = (i == jt && colg > rowg) ? -1e30f : s;
                }
            }
            // ---- online softmax (rows live in 16-lane groups) ----
            #pragma unroll
            for (int q = 0; q < 4; q++) {
                float mx = fmaxf(fmaxf(sv[0][q], sv[1][q]), fmaxf(sv[2][q], sv[3][q]));
                #pragma unroll
                for (int msk = 1; msk <= 8; msk <<= 1) mx = fmaxf(mx, __shfl_xor(mx, msk, 64));
                float mold = mrun[i][q];
                float mnew = fmaxf(mold, mx);
                float corr = __expf(mold - mnew);
                mrun[i][q] = mnew;
                float ps = 0.f;
                #pragma unroll
                for (int j_ = 0; j_ < 4; j_++) {
                    float pe = __expf(sv[j_][q] - mnew);
                    ps += pe;
                    P_lds[w][lg * 4 + q][j_ * 16 + l15] = f2bf(pe);
                }
                lrun[i][q] = lrun[i][q] * corr + ps;
                #pragma unroll
                for (int dj = 0; dj < 4; dj++) {
                    acc_o[i][dj][q] *= corr;
                }
            }
            // ---- PV: O_i += P (16x64) @ V_tile (64x64) ----
            short8 pa[2];
            #pragma unroll
            for (int kk = 0; kk < 2; kk++)
                pa[kk] = *(const short8*)&P_lds[w][l15][kk * 32 + lg * 8];
            #pragma unroll
            for (int dj = 0; dj < 4; dj++)
                #pragma unroll
                for (int kk = 0; kk < 2; kk++) {
                    short8 vf = *(const short8*)&Vt_lds[dj * 16 + l15][jt * 64 + kk * 32 + lg * 8];
                    acc_o[i][dj] = __builtin_amdgcn_mfma_f32_16x16x32_bf16(pa[kk], vf, acc_o[i][dj], 0, 0, 0);
                }
        }
    }

    // ---- epilogue: reduce l across the 16-lane group, normalize, store bf16 ----
    #pragma unroll
    for (int i = 0; i < 4; i++) {
        float inv[4];
        #pragma unroll
        for (int q = 0; q < 4; q++) {
            float ls = lrun[i][q];
            #pragma unroll
            for (int msk = 1; msk <= 8; msk <<= 1) ls += __shfl_xor(ls, msk, 64);
            inv[q] = 1.0f / ls;
        }
        #pragma unroll
        for (int dj = 0; dj < 4; dj++) {
            int colg = dj * 16 + l15;
            #pragma unroll
            for (int q = 0; q < 4; q++) {
                int rowg = 16 * (4 * i + w) + lg * 4 + q;
                att[rowbase + (size_t)rowg * C_DIM + colg] = f2bf(acc_o[i][dj][q] * inv[q]);
            }
        }
    }
}

// ---------------------------------------------------------------------------
// LM head (fp32): one block per token row; h row staged in LDS; 65 cols.
// ---------------------------------------------------------------------------
__global__ __launch_bounds__(128) void logits_kernel(const float* __restrict__ h,
                                                     const float* __restrict__ w,
                                                     const float* __restrict__ bb,
                                                     float* __restrict__ out) {
    __shared__ float hs[C_DIM];
    int n = blockIdx.x;
    for (int c = threadIdx.x; c < C_DIM; c += blockDim.x)
        hs[c] = h[(size_t)n * C_DIM + c];
    __syncthreads();
    int j = threadIdx.x;
    if (j < V_SZ) {
        float s = bb[j];
        for (int c = 0; c < C_DIM; c++) s = fmaf(hs[c], w[(size_t)c * V_SZ + j], s);
        out[(size_t)n * V_SZ + j] = s;
    }
}

__global__ __launch_bounds__(256) void rowloss_kernel(const float* __restrict__ logits,
                                                      const int* __restrict__ tgt,
                                                      float* __restrict__ rl) {
    int wave = threadIdx.x >> 6, lane = threadIdx.x & 63;
    int n = blockIdx.x * 4 + wave;
    const float* l = logits + (size_t)n * V_SZ;
    float v0 = l[lane];
    float v1 = (lane == 0) ? l[64] : -1e30f;
    float m = fmaxf(v0, v1);
    #pragma unroll
    for (int s = 32; s >= 1; s >>= 1) m = fmaxf(m, __shfl_xor(m, s, 64));
    float e = __expf(v0 - m) + ((lane == 0) ? __expf(v1 - m) : 0.f);
    #pragma unroll
    for (int s = 32; s >= 1; s >>= 1) e += __shfl_xor(e, s, 64);
    if (lane == 0) {
        float lp = l[tgt[n]] - m - logf(e);
        rl[n] = -lp;
    }
}

__global__ __launch_bounds__(256) void reduce_loss_kernel(const float* __restrict__ rl,
                                                          float* __restrict__ out_loss) {
    __shared__ float sdata[256];
    float s = 0.f;
    for (int i = threadIdx.x; i < N_TOK; i += 256) s += rl[i];
    sdata[threadIdx.x] = s;
    __syncthreads();
    for (int st = 128; st > 0; st >>= 1) {
        if (threadIdx.x < st) sdata[threadIdx.x] += sdata[threadIdx.x + st];
        __syncthreads();
    }
    if (threadIdx.x == 0) out_loss[0] = sdata[0] * (1.0f / N_TOK);
}

// ---------------------------------------------------------------------------
extern "C" void kernel_launch(void* const* d_in, const int* in_sizes, int n_in,
                              void* d_out, int out_size, void* d_ws, size_t ws_size,
                              hipStream_t stream) {
    const int*   idx     = (const int*)d_in[0];
    const int*   targets = (const int*)d_in[1];
    const float* tok_emb = (const float*)d_in[2];
    const float* pos_emb = (const float*)d_in[3];
    const float* ln1_g   = (const float*)d_in[4];
    const float* ln1_b   = (const float*)d_in[5];
    const float* wq      = (const float*)d_in[6];
    const float* wk      = (const float*)d_in[7];
    const float* wv      = (const float*)d_in[8];
    const float* wo      = (const float*)d_in[9];
    const float* bo      = (const float*)d_in[10];
    const float* ln2_g   = (const float*)d_in[11];
    const float* ln2_b   = (const float*)d_in[12];
    const float* w1      = (const float*)d_in[13];
    const float* b1      = (const float*)d_in[14];
    const float* w2      = (const float*)d_in[15];
    const float* b2      = (const float*)d_in[16];
    const float* lnf_g   = (const float*)d_in[17];
    const float* lnf_b   = (const float*)d_in[18];
    const float* lm_w    = (const float*)d_in[19];
    const float* lm_b    = (const float*)d_in[20];

    float* out = (float*)d_out;
    char*  ws  = (char*)d_ws;
    const size_t MB = 1024ull * 1024ull;
    float*   x     = (float*)(ws);               // 0..32   fp32 residual
    ushortT* h_bf  = (ushortT*)(ws + 32 * MB);   // 32..48  bf16 LN out
    ushortT* q_bf  = (ushortT*)(ws + 48 * MB);   // 48..64
    ushortT* k_bf  = (ushortT*)(ws + 64 * MB);   // 64..80
    ushortT* v_bf  = (ushortT*)(ws + 80 * MB);   // 80..96
    ushortT* att_bf= (ushortT*)(ws + 112 * MB);  // 112..128
    ushortT* ff1_bf= (ushortT*)(ws + 48 * MB);   // 48..112 (reuses q/k/v region; att untouched)
    float*   h32   = (float*)(ws + 48 * MB);     // lnf out (after last layer)
    ushortT* wqT   = (ushortT*)(ws + 128 * MB);
    ushortT* wkT   = (ushortT*)(ws + 132 * MB);
    ushortT* wvT   = (ushortT*)(ws + 136 * MB);
    ushortT* woT   = (ushortT*)(ws + 140 * MB);
    ushortT* w1T   = (ushortT*)(ws + 144 * MB);  // 16MB
    ushortT* w2T   = (ushortT*)(ws + 160 * MB);  // 16MB
    float*   rl    = (float*)(ws + 176 * MB);

    {
        dim3 gCC(C_DIM / 32, C_DIM / 32, L_N);
        tcast_kernel<<<gCC, 256, 0, stream>>>(wq, wqT, C_DIM, C_DIM);
        tcast_kernel<<<gCC, 256, 0, stream>>>(wk, wkT, C_DIM, C_DIM);
        tcast_kernel<<<gCC, 256, 0, stream>>>(wv, wvT, C_DIM, C_DIM);
        tcast_kernel<<<gCC, 256, 0, stream>>>(wo, woT, C_DIM, C_DIM);
        dim3 g1(4 * C_DIM / 32, C_DIM / 32, L_N);
        tcast_kernel<<<g1, 256, 0, stream>>>(w1, w1T, C_DIM, 4 * C_DIM);
        dim3 g2(C_DIM / 32, 4 * C_DIM / 32, L_N);
        tcast_kernel<<<g2, 256, 0, stream>>>(w2, w2T, 4 * C_DIM, C_DIM);
    }

    embed_kernel<<<(N_TOK * C_DIM / 4 + 255) / 256, 256, 0, stream>>>(idx, tok_emb, pos_emb, x);

    dim3 gemmCC(N_TOK / 128, C_DIM / 128);
    dim3 gemmC4(N_TOK / 128, 4 * C_DIM / 128);

    for (int l = 0; l < L_N; l++) {
        const ushortT* wqT_l = wqT + (size_t)l * C_DIM * C_DIM;
        const ushortT* wkT_l = wkT + (size_t)l * C_DIM * C_DIM;
        const ushortT* wvT_l = wvT + (size_t)l * C_DIM * C_DIM;
        const ushortT* woT_l = woT + (size_t)l * C_DIM * C_DIM;
        const ushortT* w1T_l = w1T + (size_t)l * C_DIM * 4 * C_DIM;
        const ushortT* w2T_l = w2T + (size_t)l * C_DIM * 4 * C_DIM;

        ln_kernel<true><<<N_TOK / 4, 256, 0, stream>>>(x, ln1_g + l * C_DIM, ln1_b + l * C_DIM, h_bf);
        gemm_bf16<1><<<gemmCC, 256, 0, stream>>>(h_bf, wqT_l, nullptr, nullptr, q_bf, N_TOK, C_DIM, C_DIM);
        gemm_bf16<1><<<gemmCC, 256, 0, stream>>>(h_bf, wkT_l, nullptr, nullptr, k_bf, N_TOK, C_DIM, C_DIM);
        gemm_bf16<1><<<gemmCC, 256, 0, stream>>>(h_bf, wvT_l, nullptr, nullptr, v_bf, N_TOK, C_DIM, C_DIM);
        attn_kernel<<<64 * H_N, 256, 0, stream>>>(q_bf, k_bf, v_bf, att_bf);
        gemm_bf16<3><<<gemmCC, 256, 0, stream>>>(att_bf, woT_l, bo + l * C_DIM, x, x, N_TOK, C_DIM, C_DIM);
        ln_kernel<true><<<N_TOK / 4, 256, 0, stream>>>(x, ln2_g + l * C_DIM, ln2_b + l * C_DIM, h_bf);
        gemm_bf16<2><<<gemmC4, 256, 0, stream>>>(h_bf, w1T_l, b1 + (size_t)l * 4 * C_DIM, nullptr, ff1_bf, N_TOK, 4 * C_DIM, C_DIM);
        gemm_bf16<3><<<gemmCC, 256, 0, stream>>>(ff1_bf, w2T_l, b2 + l * C_DIM, x, x, N_TOK, C_DIM, 4 * C_DIM);
    }

    ln_kernel<false><<<N_TOK / 4, 256, 0, stream>>>(x, lnf_g, lnf_b, h32);
    logits_kernel<<<N_TOK, 128, 0, stream>>>(h32, lm_w, lm_b, out);

    rowloss_kernel<<<N_TOK / 4, 256, 0, stream>>>(out, targets, rl);
    reduce_loss_kernel<<<1, 256, 0, stream>>>(rl, out + (size_t)N_TOK * V_SZ);
}

// Round 4
// 1727.624 us; speedup vs baseline: 8.0802x; 1.1785x over previous
//
#include <hip/hip_runtime.h>
#include <math.h>

#define V_SZ   65
#define C_DIM  512
#define T_SEQ  256
#define H_N    8
#define HS_D   64
#define L_N    8
#define N_TOK  16384   // B*T = 64*256
#define LN_EPS 1e-5f
#define SM_SCALE 0.044194173824159216f  // 512^-0.5 (scaled by n_embd, per reference)

typedef unsigned short ushortT;
typedef __attribute__((ext_vector_type(8))) short    short8;
typedef __attribute__((ext_vector_type(8))) ushortT  ushort8;
typedef __attribute__((ext_vector_type(4))) float    f32x4;

typedef __attribute__((address_space(3))) unsigned int        lds_uint;
typedef const __attribute__((address_space(1))) unsigned int  glob_uint;

__device__ inline ushortT f2bf(float f) {
    unsigned int u = __float_as_uint(f);
    u = (u + 0x7fffu + ((u >> 16) & 1u)) >> 16;   // RNE
    return (ushortT)u;
}
__device__ inline float bf2f(ushortT u) {
    return __uint_as_float(((unsigned int)u) << 16);
}

// ---------------------------------------------------------------------------
// Embedding
// ---------------------------------------------------------------------------
__global__ void embed_kernel(const int* __restrict__ idx,
                             const float* __restrict__ tok,
                             const float* __restrict__ pos,
                             float* __restrict__ x) {
    int i = blockIdx.x * blockDim.x + threadIdx.x;
    const int NF4 = N_TOK * C_DIM / 4;
    if (i >= NF4) return;
    int c4 = i % (C_DIM / 4);
    int n  = i / (C_DIM / 4);
    int t  = n % T_SEQ;
    int tk = idx[n];
    float4 a = ((const float4*)tok)[(size_t)tk * (C_DIM/4) + c4];
    float4 p = ((const float4*)pos)[(size_t)t  * (C_DIM/4) + c4];
    float4 r; r.x=a.x+p.x; r.y=a.y+p.y; r.z=a.z+p.z; r.w=a.w+p.w;
    ((float4*)x)[i] = r;
}

// ---------------------------------------------------------------------------
// Weight transpose+cast: src[K][N] f32 -> dst[N][K] bf16, batched over L.
// ---------------------------------------------------------------------------
__global__ __launch_bounds__(256) void tcast_kernel(const float* __restrict__ src,
                                                    ushortT* __restrict__ dst,
                                                    int K, int N) {
    __shared__ float tile[32][33];
    size_t lo = (size_t)blockIdx.z * K * N;
    int n0 = blockIdx.x * 32, k0 = blockIdx.y * 32;
    int tx = threadIdx.x & 31, ty = threadIdx.x >> 5;
    #pragma unroll
    for (int s = 0; s < 4; s++) {
        int kk = ty + s * 8;
        tile[kk][tx] = src[lo + (size_t)(k0 + kk) * N + n0 + tx];
    }
    __syncthreads();
    #pragma unroll
    for (int s = 0; s < 4; s++) {
        int nn = ty + s * 8;
        dst[lo + (size_t)(n0 + nn) * K + k0 + tx] = f2bf(tile[tx][nn]);
    }
}

// lm head weight: lm_w[512][65] f32 -> lmT[128][512] bf16 (rows >=65 zero)
__global__ __launch_bounds__(256) void lmcast_kernel(const float* __restrict__ w,
                                                     ushortT* __restrict__ dst) {
    int n = blockIdx.x;            // 0..127
    for (int k = threadIdx.x; k < C_DIM; k += 256)
        dst[(size_t)n * C_DIM + k] = (n < V_SZ) ? f2bf(w[(size_t)k * V_SZ + n]) : (ushortT)0;
}

// ---------------------------------------------------------------------------
// LayerNorm: one wave per row of C=512, float4 loads.
// ---------------------------------------------------------------------------
template<bool BF16OUT>
__global__ __launch_bounds__(256) void ln_kernel(const float* __restrict__ in,
                                                 const float* __restrict__ g,
                                                 const float* __restrict__ b,
                                                 void* __restrict__ outv) {
    int wave = threadIdx.x >> 6;
    int lane = threadIdx.x & 63;
    int row  = blockIdx.x * 4 + wave;
    const float4* r4 = (const float4*)(in + (size_t)row * C_DIM);
    float v[8];
    *(float4*)&v[0] = r4[lane * 2];
    *(float4*)&v[4] = r4[lane * 2 + 1];
    float s = 0.f;
    #pragma unroll
    for (int k = 0; k < 8; k++) s += v[k];
    #pragma unroll
    for (int m = 32; m >= 1; m >>= 1) s += __shfl_xor(s, m, 64);
    float mean = s * (1.0f / C_DIM);
    float vs = 0.f;
    #pragma unroll
    for (int k = 0; k < 8; k++) { float d = v[k] - mean; vs += d * d; }
    #pragma unroll
    for (int m = 32; m >= 1; m >>= 1) vs += __shfl_xor(vs, m, 64);
    float rstd = rsqrtf(vs * (1.0f / C_DIM) + LN_EPS);
    float gv[8], bv[8];
    *(float4*)&gv[0] = *(const float4*)&g[lane * 8];
    *(float4*)&gv[4] = *(const float4*)&g[lane * 8 + 4];
    *(float4*)&bv[0] = *(const float4*)&b[lane * 8];
    *(float4*)&bv[4] = *(const float4*)&b[lane * 8 + 4];
    if (BF16OUT) {
        ushort8 pack;
        #pragma unroll
        for (int k = 0; k < 8; k++) pack[k] = f2bf((v[k] - mean) * rstd * gv[k] + bv[k]);
        *(ushort8*)&((ushortT*)outv)[(size_t)row * C_DIM + lane * 8] = pack;
    } else {
        float o[8];
        #pragma unroll
        for (int k = 0; k < 8; k++) o[k] = (v[k] - mean) * rstd * gv[k] + bv[k];
        float4* o4 = (float4*)&((float*)outv)[(size_t)row * C_DIM + lane * 8];
        o4[0] = *(float4*)&o[0];
        o4[1] = *(float4*)&o[4];
    }
}

// ---------------------------------------------------------------------------
// bf16 MFMA GEMM core: C[M,N] = epi(A[M,K] @ Bt[N,K]^T)
// 128x128 tile, BK=32, 4 waves (2x2). Staging via global_load_lds width=16,
// linear LDS [128][32] with k-slot XOR swizzle applied on BOTH the global
// source address and the ds_read offset (rule #21: both-sides-or-neither).
// EPI: 1 bf16 | 2 +bias,relu -> bf16 | 3 +bias,+res -> fp32 | 4 lm head
// ---------------------------------------------------------------------------
template<int EPI>
__device__ __forceinline__ void gemm_core(const ushortT* __restrict__ A,
                                          const ushortT* __restrict__ Bt,
                                          const float* __restrict__ bias,
                                          const float* __restrict__ res,
                                          void* __restrict__ outp,
                                          int N, int K,
                                          int mBase, int nBase) {
    __shared__ __align__(16) ushortT As[128 * 32];
    __shared__ __align__(16) ushortT Bs[128 * 32];
    const int tid = threadIdx.x;
    const int w = tid >> 6, lane = tid & 63;
    const int wr = w >> 1, wc = w & 1;
    const int l15 = lane & 15, lg = lane >> 4;

    // staging: wave w covers rows w*32..w*32+31 in two 16-row issues.
    // lane l -> row r0 + (l>>2), physical 16B slot (l&3); fetches logical
    // k-slot ks = slot ^ ((r>>1)&3)  (the swizzle).
    const int srow = (lane >> 2);
    const int sslot = lane & 3;

    f32x4 acc[4][4];
    #pragma unroll
    for (int i = 0; i < 4; i++)
        #pragma unroll
        for (int j = 0; j < 4; j++)
            acc[i][j] = {0.f, 0.f, 0.f, 0.f};

    for (int k0 = 0; k0 < K; k0 += 32) {
        #pragma unroll
        for (int t = 0; t < 2; t++) {
            int r = w * 32 + t * 16 + srow;
            int ks = sslot ^ ((r >> 1) & 3);
            const ushortT* ga = &A[(size_t)(mBase + r) * K + k0 + ks * 8];
            __builtin_amdgcn_global_load_lds((glob_uint*)ga,
                (lds_uint*)&As[(w * 32 + t * 16) * 32], 16, 0, 0);
            const ushortT* gb = &Bt[(size_t)(nBase + r) * K + k0 + ks * 8];
            __builtin_amdgcn_global_load_lds((glob_uint*)gb,
                (lds_uint*)&Bs[(w * 32 + t * 16) * 32], 16, 0, 0);
        }
        __syncthreads();
        short8 af[4], bfr[4];
        #pragma unroll
        for (int i = 0; i < 4; i++) {
            int r = wr * 64 + i * 16 + l15;
            int cb = (lg * 16) ^ (((r >> 1) & 3) << 4);
            af[i] = *(const short8*)((const char*)As + r * 64 + cb);
        }
        #pragma unroll
        for (int j = 0; j < 4; j++) {
            int r = wc * 64 + j * 16 + l15;
            int cb = (lg * 16) ^ (((r >> 1) & 3) << 4);
            bfr[j] = *(const short8*)((const char*)Bs + r * 64 + cb);
        }
        #pragma unroll
        for (int i = 0; i < 4; i++)
            #pragma unroll
            for (int j = 0; j < 4; j++)
                acc[i][j] = __builtin_amdgcn_mfma_f32_16x16x32_bf16(af[i], bfr[j], acc[i][j], 0, 0, 0);
        __syncthreads();
    }

    // epilogue: C/D layout col=lane&15, row=(lane>>4)*4+q  [m89-verified]
    int lr = lg * 4;
    #pragma unroll
    for (int i = 0; i < 4; i++) {
        #pragma unroll
        for (int j = 0; j < 4; j++) {
            int col = nBase + wc * 64 + j * 16 + l15;
            if (EPI == 4 && col >= V_SZ) continue;
            #pragma unroll
            for (int q = 0; q < 4; q++) {
                size_t row = (size_t)(mBase + wr * 64 + i * 16 + lr + q);
                float vv = acc[i][j][q];
                if (EPI >= 2) vv += bias[col];
                if (EPI == 2) vv = fmaxf(vv, 0.f);
                if (EPI == 3) vv += res[row * N + col];
                if (EPI == 1)      ((ushortT*)outp)[row * N + col] = f2bf(vv);
                else if (EPI == 2) ((ushortT*)outp)[row * N + col] = f2bf(vv);
                else if (EPI == 3) ((float*)outp)[row * N + col]   = vv;
                else               ((float*)outp)[row * V_SZ + col] = vv;   // EPI 4
            }
        }
    }
}

template<int EPI>
__global__ __launch_bounds__(256, 2) void gemm_bf16(const ushortT* __restrict__ A,
                                                    const ushortT* __restrict__ Bt,
                                                    const float* __restrict__ bias,
                                                    const float* __restrict__ res,
                                                    void* __restrict__ outp,
                                                    int N, int K) {
    gemm_core<EPI>(A, Bt, bias, res, outp, N, K, blockIdx.x * 128, blockIdx.y * 128);
}

// fused q/k/v projection: blockIdx.z picks weight + destination
__global__ __launch_bounds__(256, 2) void gemm_qkv(const ushortT* __restrict__ A,
                                                   const ushortT* __restrict__ bq,
                                                   const ushortT* __restrict__ bk,
                                                   const ushortT* __restrict__ bv,
                                                   ushortT* __restrict__ oq,
                                                   ushortT* __restrict__ ok,
                                                   ushortT* __restrict__ ov,
                                                   int N, int K) {
    const ushortT* Bt = (blockIdx.z == 0) ? bq : (blockIdx.z == 1) ? bk : bv;
    ushortT*       o  = (blockIdx.z == 0) ? oq : (blockIdx.z == 1) ? ok : ov;
    gemm_core<1>(A, Bt, nullptr, nullptr, o, N, K, blockIdx.x * 128, blockIdx.y * 128);
}

// ---------------------------------------------------------------------------
// MFMA flash attention (unchanged from round 3; passing, balanced causal).
// ---------------------------------------------------------------------------
__global__ __launch_bounds__(256) void attn_kernel(const ushortT* __restrict__ qp,
                                                   const ushortT* __restrict__ kp,
                                                   const ushortT* __restrict__ vp,
                                                   ushortT* __restrict__ att) {
    __shared__ ushortT K_lds[T_SEQ][72];
    __shared__ ushortT Vt_lds[HS_D][264];
    __shared__ ushortT P_lds[4][16][72];
    int bh = blockIdx.x;
    int b = bh >> 3, h = bh & 7;
    int tid = threadIdx.x;
    int w = tid >> 6, lane = tid & 63;
    const size_t rowbase = (size_t)b * T_SEQ * C_DIM + (size_t)h * HS_D;
    int l15 = lane & 15, lg = lane >> 4;

    #pragma unroll
    for (int it = 0; it < 8; it++) {
        int f = tid + it * 256;
        int r = f >> 3, c8 = f & 7;
        ushort8 kb = *(const ushort8*)&kp[rowbase + (size_t)r * C_DIM + c8 * 8];
        *(ushort8*)&K_lds[r][c8 * 8] = kb;
        ushort8 vb = *(const ushort8*)&vp[rowbase + (size_t)r * C_DIM + c8 * 8];
        #pragma unroll
        for (int e = 0; e < 8; e++) Vt_lds[c8 * 8 + e][r] = vb[e];
    }

    short8 qf[4][2];
    #pragma unroll
    for (int i = 0; i < 4; i++) {
        int grow = 16 * (4 * i + w) + l15;
        #pragma unroll
        for (int kk = 0; kk < 2; kk++)
            qf[i][kk] = *(const short8*)&qp[rowbase + (size_t)grow * C_DIM + kk * 32 + lg * 8];
    }
    __syncthreads();

    f32x4 acc_o[4][4];
    float mrun[4][4], lrun[4][4];
    #pragma unroll
    for (int i = 0; i < 4; i++) {
        #pragma unroll
        for (int j = 0; j < 4; j++) acc_o[i][j] = {0.f, 0.f, 0.f, 0.f};
        #pragma unroll
        for (int q = 0; q < 4; q++) { mrun[i][q] = -1e30f; lrun[i][q] = 0.f; }
    }

    #pragma unroll
    for (int jt = 0; jt < 4; jt++) {
        #pragma unroll
        for (int i = 0; i < 4; i++) {
            if (i < jt) continue;
            f32x4 acc_s[4];
            #pragma unroll
            for (int j_ = 0; j_ < 4; j_++) acc_s[j_] = {0.f, 0.f, 0.f, 0.f};
            #pragma unroll
            for (int j_ = 0; j_ < 4; j_++)
                #pragma unroll
                for (int kk = 0; kk < 2; kk++) {
                    short8 kf = *(const short8*)&K_lds[jt * 64 + j_ * 16 + l15][kk * 32 + lg * 8];
                    acc_s[j_] = __builtin_amdgcn_mfma_f32_16x16x32_bf16(qf[i][kk], kf, acc_s[j_], 0, 0, 0);
                }
            float sv[4][4];
            #pragma unroll
            for (int j_ = 0; j_ < 4; j_++) {
                int colg = jt * 64 + j_ * 16 + l15;
                #pragma unroll
                for (int q = 0; q < 4; q++) {
                    int rowg = 16 * (4 * i + w) + lg * 4 + q;
                    float s = acc_s[j_][q] * SM_SCALE;
                    sv[j_][q] = (i == jt && colg > rowg) ? -1e30f : s;
                }
            }
            #pragma unroll
            for (int q = 0; q < 4; q++) {
                float mx = fmaxf(fmaxf(sv[0][q], sv[1][q]), fmaxf(sv[2][q], sv[3][q]));
                #pragma unroll
                for (int msk = 1; msk <= 8; msk <<= 1) mx = fmaxf(mx, __shfl_xor(mx, msk, 64));
                float mold = mrun[i][q];
                float mnew = fmaxf(mold, mx);
                float corr = __expf(mold - mnew);
                mrun[i][q] = mnew;
                float ps = 0.f;
                #pragma unroll
                for (int j_ = 0; j_ < 4; j_++) {
                    float pe = __expf(sv[j_][q] - mnew);
                    ps += pe;
                    P_lds[w][lg * 4 + q][j_ * 16 + l15] = f2bf(pe);
                }
                lrun[i][q] = lrun[i][q] * corr + ps;
                #pragma unroll
                for (int dj = 0; dj < 4; dj++) acc_o[i][dj][q] *= corr;
            }
            short8 pa[2];
            #pragma unroll
            for (int kk = 0; kk < 2; kk++)
                pa[kk] = *(const short8*)&P_lds[w][l15][kk * 32 + lg * 8];
            #pragma unroll
            for (int dj = 0; dj < 4; dj++)
                #pragma unroll
                for (int kk = 0; kk < 2; kk++) {
                    short8 vf = *(const short8*)&Vt_lds[dj * 16 + l15][jt * 64 + kk * 32 + lg * 8];
                    acc_o[i][dj] = __builtin_amdgcn_mfma_f32_16x16x32_bf16(pa[kk], vf, acc_o[i][dj], 0, 0, 0);
                }
        }
    }

    #pragma unroll
    for (int i = 0; i < 4; i++) {
        float inv[4];
        #pragma unroll
        for (int q = 0; q < 4; q++) {
            float ls = lrun[i][q];
            #pragma unroll
            for (int msk = 1; msk <= 8; msk <<= 1) ls += __shfl_xor(ls, msk, 64);
            inv[q] = 1.0f / ls;
        }
        #pragma unroll
        for (int dj = 0; dj < 4; dj++) {
            int colg = dj * 16 + l15;
            #pragma unroll
            for (int q = 0; q < 4; q++) {
                int rowg = 16 * (4 * i + w) + lg * 4 + q;
                att[rowbase + (size_t)rowg * C_DIM + colg] = f2bf(acc_o[i][dj][q] * inv[q]);
            }
        }
    }
}

// ---------------------------------------------------------------------------
// Loss
// ---------------------------------------------------------------------------
__global__ __launch_bounds__(256) void rowloss_kernel(const float* __restrict__ logits,
                                                      const int* __restrict__ tgt,
                                                      float* __restrict__ rl) {
    int wave = threadIdx.x >> 6, lane = threadIdx.x & 63;
    int n = blockIdx.x * 4 + wave;
    const float* l = logits + (size_t)n * V_SZ;
    float v0 = l[lane];
    float v1 = (lane == 0) ? l[64] : -1e30f;
    float m = fmaxf(v0, v1);
    #pragma unroll
    for (int s = 32; s >= 1; s >>= 1) m = fmaxf(m, __shfl_xor(m, s, 64));
    float e = __expf(v0 - m) + ((lane == 0) ? __expf(v1 - m) : 0.f);
    #pragma unroll
    for (int s = 32; s >= 1; s >>= 1) e += __shfl_xor(e, s, 64);
    if (lane == 0) {
        float lp = l[tgt[n]] - m - logf(e);
        rl[n] = -lp;
    }
}

__global__ __launch_bounds__(256) void reduce_loss_kernel(const float* __restrict__ rl,
                                                          float* __restrict__ out_loss) {
    __shared__ float sdata[256];
    float s = 0.f;
    for (int i = threadIdx.x; i < N_TOK; i += 256) s += rl[i];
    sdata[threadIdx.x] = s;
    __syncthreads();
    for (int st = 128; st > 0; st >>= 1) {
        if (threadIdx.x < st) sdata[threadIdx.x] += sdata[threadIdx.x + st];
        __syncthreads();
    }
    if (threadIdx.x == 0) out_loss[0] = sdata[0] * (1.0f / N_TOK);
}

// ---------------------------------------------------------------------------
extern "C" void kernel_launch(void* const* d_in, const int* in_sizes, int n_in,
                              void* d_out, int out_size, void* d_ws, size_t ws_size,
                              hipStream_t stream) {
    const int*   idx     = (const int*)d_in[0];
    const int*   targets = (const int*)d_in[1];
    const float* tok_emb = (const float*)d_in[2];
    const float* pos_emb = (const float*)d_in[3];
    const float* ln1_g   = (const float*)d_in[4];
    const float* ln1_b   = (const float*)d_in[5];
    const float* wq      = (const float*)d_in[6];
    const float* wk      = (const float*)d_in[7];
    const float* wv      = (const float*)d_in[8];
    const float* wo      = (const float*)d_in[9];
    const float* bo      = (const float*)d_in[10];
    const float* ln2_g   = (const float*)d_in[11];
    const float* ln2_b   = (const float*)d_in[12];
    const float* w1      = (const float*)d_in[13];
    const float* b1      = (const float*)d_in[14];
    const float* w2      = (const float*)d_in[15];
    const float* b2      = (const float*)d_in[16];
    const float* lnf_g   = (const float*)d_in[17];
    const float* lnf_b   = (const float*)d_in[18];
    const float* lm_w    = (const float*)d_in[19];
    const float* lm_b    = (const float*)d_in[20];

    float* out = (float*)d_out;
    char*  ws  = (char*)d_ws;
    const size_t MB = 1024ull * 1024ull;
    float*   x     = (float*)(ws);               // 0..32   fp32 residual
    ushortT* h_bf  = (ushortT*)(ws + 32 * MB);   // 32..48  bf16 LN out
    ushortT* q_bf  = (ushortT*)(ws + 48 * MB);   // 48..64
    ushortT* k_bf  = (ushortT*)(ws + 64 * MB);   // 64..80
    ushortT* v_bf  = (ushortT*)(ws + 80 * MB);   // 80..96
    ushortT* att_bf= (ushortT*)(ws + 112 * MB);  // 112..128
    ushortT* ff1_bf= (ushortT*)(ws + 48 * MB);   // 48..112 (reuses q/k/v)
    ushortT* wqT   = (ushortT*)(ws + 128 * MB);
    ushortT* wkT   = (ushortT*)(ws + 132 * MB);
    ushortT* wvT   = (ushortT*)(ws + 136 * MB);
    ushortT* woT   = (ushortT*)(ws + 140 * MB);
    ushortT* w1T   = (ushortT*)(ws + 144 * MB);  // 16MB
    ushortT* w2T   = (ushortT*)(ws + 160 * MB);  // 16MB
    float*   rl    = (float*)(ws + 176 * MB);    // 64KB
    ushortT* lmT   = (ushortT*)(ws + 177 * MB);  // 128KB

    {
        dim3 gCC(C_DIM / 32, C_DIM / 32, L_N);
        tcast_kernel<<<gCC, 256, 0, stream>>>(wq, wqT, C_DIM, C_DIM);
        tcast_kernel<<<gCC, 256, 0, stream>>>(wk, wkT, C_DIM, C_DIM);
        tcast_kernel<<<gCC, 256, 0, stream>>>(wv, wvT, C_DIM, C_DIM);
        tcast_kernel<<<gCC, 256, 0, stream>>>(wo, woT, C_DIM, C_DIM);
        dim3 g1(4 * C_DIM / 32, C_DIM / 32, L_N);
        tcast_kernel<<<g1, 256, 0, stream>>>(w1, w1T, C_DIM, 4 * C_DIM);
        dim3 g2(C_DIM / 32, 4 * C_DIM / 32, L_N);
        tcast_kernel<<<g2, 256, 0, stream>>>(w2, w2T, 4 * C_DIM, C_DIM);
        lmcast_kernel<<<128, 256, 0, stream>>>(lm_w, lmT);
    }

    embed_kernel<<<(N_TOK * C_DIM / 4 + 255) / 256, 256, 0, stream>>>(idx, tok_emb, pos_emb, x);

    dim3 gemmCC(N_TOK / 128, C_DIM / 128);
    dim3 gemmC4(N_TOK / 128, 4 * C_DIM / 128);
    dim3 gemmQKV(N_TOK / 128, C_DIM / 128, 3);

    for (int l = 0; l < L_N; l++) {
        const ushortT* wqT_l = wqT + (size_t)l * C_DIM * C_DIM;
        const ushortT* wkT_l = wkT + (size_t)l * C_DIM * C_DIM;
        const ushortT* wvT_l = wvT + (size_t)l * C_DIM * C_DIM;
        const ushortT* woT_l = woT + (size_t)l * C_DIM * C_DIM;
        const ushortT* w1T_l = w1T + (size_t)l * C_DIM * 4 * C_DIM;
        const ushortT* w2T_l = w2T + (size_t)l * C_DIM * 4 * C_DIM;

        ln_kernel<true><<<N_TOK / 4, 256, 0, stream>>>(x, ln1_g + l * C_DIM, ln1_b + l * C_DIM, h_bf);
        gemm_qkv<<<gemmQKV, 256, 0, stream>>>(h_bf, wqT_l, wkT_l, wvT_l, q_bf, k_bf, v_bf, C_DIM, C_DIM);
        attn_kernel<<<64 * H_N, 256, 0, stream>>>(q_bf, k_bf, v_bf, att_bf);
        gemm_bf16<3><<<gemmCC, 256, 0, stream>>>(att_bf, woT_l, bo + l * C_DIM, x, x, C_DIM, C_DIM);
        ln_kernel<true><<<N_TOK / 4, 256, 0, stream>>>(x, ln2_g + l * C_DIM, ln2_b + l * C_DIM, h_bf);
        gemm_bf16<2><<<gemmC4, 256, 0, stream>>>(h_bf, w1T_l, b1 + (size_t)l * 4 * C_DIM, nullptr, ff1_bf, 4 * C_DIM, C_DIM);
        gemm_bf16<3><<<gemmCC, 256, 0, stream>>>(ff1_bf, w2T_l, b2 + l * C_DIM, x, x, C_DIM, 4 * C_DIM);
    }

    // final LN (bf16) + MFMA LM head -> f32 logits
    ln_kernel<true><<<N_TOK / 4, 256, 0, stream>>>(x, lnf_g, lnf_b, h_bf);
    gemm_bf16<4><<<dim3(N_TOK / 128, 1), 256, 0, stream>>>(h_bf, lmT, lm_b, nullptr, out, V_SZ, C_DIM);

    rowloss_kernel<<<N_TOK / 4, 256, 0, stream>>>(out, targets, rl);
    reduce_loss_kernel<<<1, 256, 0, stream>>>(rl, out + (size_t)N_TOK * V_SZ);
}